// Round 1
// baseline (196.575 us; speedup 1.0000x reference)
//
#include <hip/hip_runtime.h>

// LocalizationLoss: B=1048576, N=3, C=7. output (B,3,7) fp32, target (B,3,5) fp32.
// result = (5*(Sx+Sy+2*Swh) + 3*Sce - 0.5*Sbce)/(B*N) + 0.5   (scalar fp32)

#define NBLK 4096          // B / 256
#define ROWS_PER_BLK 256
#define OUT_F (ROWS_PER_BLK * 21)   // 5376 floats per block chunk
#define TGT_F (ROWS_PER_BLK * 15)   // 3840 floats per block chunk
#define INV_BN (1.0f / 3145728.0f)

__global__ __launch_bounds__(256) void loc_loss_kernel(
    const float* __restrict__ gout, const float* __restrict__ gtgt,
    float* __restrict__ ws) {
  __shared__ float s_out[OUT_F];
  __shared__ float s_tgt[TGT_F];
  __shared__ float s_wave[4];

  const int tid = threadIdx.x;
  // Coalesced float4 staging. Block chunk bases: 21504B / 15360B -> 16B aligned.
  const float4* go4 = (const float4*)(gout + (size_t)blockIdx.x * OUT_F);
  const float4* gt4 = (const float4*)(gtgt + (size_t)blockIdx.x * TGT_F);
  float4* so4 = (float4*)s_out;
  float4* st4 = (float4*)s_tgt;
  #pragma unroll
  for (int i = 0; i < 5; ++i) so4[tid + 256 * i] = go4[tid + 256 * i];
  if (tid < (OUT_F / 4 - 5 * 256)) so4[tid + 5 * 256] = go4[tid + 5 * 256];  // 64
  #pragma unroll
  for (int i = 0; i < 3; ++i) st4[tid + 256 * i] = gt4[tid + 256 * i];
  if (tid < (TGT_F / 4 - 3 * 256)) st4[tid + 3 * 256] = gt4[tid + 3 * 256];  // 192
  __syncthreads();

  // One row per thread. LDS strides 21/15 are odd -> conflict-free on 32 banks.
  const float* o = s_out + tid * 21;
  const float* t = s_tgt + tid * 15;

  float sbce = 0.f, sce = 0.f, sx = 0.f, sy = 0.f, swh = 0.f;
  float L[3][3];
  int cls[3];
  #pragma unroll
  for (int n = 0; n < 3; ++n) {
    const float p  = o[n * 7 + 0];
    const float tt = t[n * 5 + 0];
    sbce += tt * __logf(p) + (1.f - tt) * __logf(1.f - p);
    const bool mk = (tt != 0.f);
    const float m = mk ? 1.f : 0.f;
    const float dx = o[n * 7 + 1] * m - t[n * 5 + 1];
    sx += dx * dx;
    const float dy = o[n * 7 + 2] * m - t[n * 5 + 2];
    sy += dy * dy;
    const float sp = mk ? __builtin_sqrtf(o[n * 7 + 3]) : 0.f;
    const float dw = sp - __builtin_sqrtf(t[n * 5 + 3]);
    swh += dw * dw;
    L[n][0] = o[n * 7 + 4] * m;
    L[n][1] = o[n * 7 + 5] * m;
    L[n][2] = o[n * 7 + 6] * m;
    cls[n] = (int)t[n * 5 + 4];
  }
  // log-softmax over anchor axis per class channel j; nll[j] = lse_j - L[cls[j]][j]
  #pragma unroll
  for (int j = 0; j < 3; ++j) {
    // logits are in [0,1] (masked) -> no max-subtraction needed for exp stability
    const float e = __expf(L[0][j]) + __expf(L[1][j]) + __expf(L[2][j]);
    const float lse = __logf(e);
    const int idx = cls[j];
    const float sel = (idx == 0) ? L[0][j] : ((idx == 1) ? L[1][j] : L[2][j]);
    sce += lse - sel;
  }

  float acc = 5.f * (sx + sy + 2.f * swh) + 3.f * sce - 0.5f * sbce;

  // wave-64 butterfly reduce, then 4 wave leaders -> LDS -> one atomic per block
  #pragma unroll
  for (int off = 32; off > 0; off >>= 1) acc += __shfl_down(acc, off, 64);
  if ((tid & 63) == 0) s_wave[tid >> 6] = acc;
  __syncthreads();
  if (tid == 0) {
    atomicAdd(ws, s_wave[0] + s_wave[1] + s_wave[2] + s_wave[3]);
  }
}

__global__ void loc_loss_finalize(const float* __restrict__ ws,
                                  float* __restrict__ out) {
  out[0] = ws[0] * INV_BN + 0.5f;
}

extern "C" void kernel_launch(void* const* d_in, const int* in_sizes, int n_in,
                              void* d_out, int out_size, void* d_ws, size_t ws_size,
                              hipStream_t stream) {
  const float* gout = (const float*)d_in[0];  // (B,3,7)
  const float* gtgt = (const float*)d_in[1];  // (B,3,5)
  float* ws = (float*)d_ws;
  float* out = (float*)d_out;

  hipMemsetAsync(ws, 0, sizeof(float), stream);  // ws re-poisoned each launch
  loc_loss_kernel<<<NBLK, 256, 0, stream>>>(gout, gtgt, ws);
  loc_loss_finalize<<<1, 1, 0, stream>>>(ws, out);
}

// Round 2
// 175.934 us; speedup vs baseline: 1.1173x; 1.1173x over previous
//
#include <hip/hip_runtime.h>

// LocalizationLoss: B=1048576, N=3, C=7. output (B,3,7) fp32, target (B,3,5) fp32.
// result = (5*(Sx+Sy+2*Swh) + 3*Sce - 0.5*Sbce)/(B*N) + 0.5   (scalar fp32)
//
// R1: replaced single-address atomicAdd (4096 serialized cross-XCD RMWs ~= the
// entire 77us of R0) with per-block partials in ws + a tiny finalize reduce.
// Also drops the memset dispatch (partials are overwritten, no init needed).

#define NBLK 4096          // B / 256
#define ROWS_PER_BLK 256
#define OUT_F (ROWS_PER_BLK * 21)   // 5376 floats per block chunk
#define TGT_F (ROWS_PER_BLK * 15)   // 3840 floats per block chunk
#define INV_BN (1.0f / 3145728.0f)

__global__ __launch_bounds__(256) void loc_loss_kernel(
    const float* __restrict__ gout, const float* __restrict__ gtgt,
    float* __restrict__ ws) {
  __shared__ float s_out[OUT_F];
  __shared__ float s_tgt[TGT_F];
  __shared__ float s_wave[4];

  const int tid = threadIdx.x;
  // Coalesced float4 staging. Block chunk bases: 21504B / 15360B -> 16B aligned.
  const float4* go4 = (const float4*)(gout + (size_t)blockIdx.x * OUT_F);
  const float4* gt4 = (const float4*)(gtgt + (size_t)blockIdx.x * TGT_F);
  float4* so4 = (float4*)s_out;
  float4* st4 = (float4*)s_tgt;
  #pragma unroll
  for (int i = 0; i < 5; ++i) so4[tid + 256 * i] = go4[tid + 256 * i];
  if (tid < (OUT_F / 4 - 5 * 256)) so4[tid + 5 * 256] = go4[tid + 5 * 256];  // 64
  #pragma unroll
  for (int i = 0; i < 3; ++i) st4[tid + 256 * i] = gt4[tid + 256 * i];
  if (tid < (TGT_F / 4 - 3 * 256)) st4[tid + 3 * 256] = gt4[tid + 3 * 256];  // 192
  __syncthreads();

  // One row per thread. LDS strides 21/15 are odd -> conflict-free on 32 banks.
  const float* o = s_out + tid * 21;
  const float* t = s_tgt + tid * 15;

  float sbce = 0.f, sce = 0.f, sx = 0.f, sy = 0.f, swh = 0.f;
  float L[3][3];
  int cls[3];
  #pragma unroll
  for (int n = 0; n < 3; ++n) {
    const float p  = o[n * 7 + 0];
    const float tt = t[n * 5 + 0];
    sbce += tt * __logf(p) + (1.f - tt) * __logf(1.f - p);
    const bool mk = (tt != 0.f);
    const float m = mk ? 1.f : 0.f;
    const float dx = o[n * 7 + 1] * m - t[n * 5 + 1];
    sx += dx * dx;
    const float dy = o[n * 7 + 2] * m - t[n * 5 + 2];
    sy += dy * dy;
    const float sp = mk ? __builtin_sqrtf(o[n * 7 + 3]) : 0.f;
    const float dw = sp - __builtin_sqrtf(t[n * 5 + 3]);
    swh += dw * dw;
    L[n][0] = o[n * 7 + 4] * m;
    L[n][1] = o[n * 7 + 5] * m;
    L[n][2] = o[n * 7 + 6] * m;
    cls[n] = (int)t[n * 5 + 4];
  }
  // log-softmax over anchor axis per class channel j; nll[j] = lse_j - L[cls[j]][j]
  #pragma unroll
  for (int j = 0; j < 3; ++j) {
    // logits are in [0,1] (masked) -> no max-subtraction needed for exp stability
    const float e = __expf(L[0][j]) + __expf(L[1][j]) + __expf(L[2][j]);
    const float lse = __logf(e);
    const int idx = cls[j];
    const float sel = (idx == 0) ? L[0][j] : ((idx == 1) ? L[1][j] : L[2][j]);
    sce += lse - sel;
  }

  float acc = 5.f * (sx + sy + 2.f * swh) + 3.f * sce - 0.5f * sbce;

  // wave-64 butterfly reduce, then 4 wave leaders -> LDS -> one partial per block
  #pragma unroll
  for (int off = 32; off > 0; off >>= 1) acc += __shfl_down(acc, off, 64);
  if ((tid & 63) == 0) s_wave[tid >> 6] = acc;
  __syncthreads();
  if (tid == 0) {
    ws[blockIdx.x] = s_wave[0] + s_wave[1] + s_wave[2] + s_wave[3];
  }
}

__global__ __launch_bounds__(256) void loc_loss_finalize(
    const float* __restrict__ ws, float* __restrict__ out) {
  __shared__ float s_wave[4];
  const int tid = threadIdx.x;
  const float4* w4 = (const float4*)ws;  // 4096 partials = 1024 float4
  float acc = 0.f;
  #pragma unroll
  for (int i = 0; i < 4; ++i) {
    float4 v = w4[tid + 256 * i];
    acc += (v.x + v.y) + (v.z + v.w);
  }
  #pragma unroll
  for (int off = 32; off > 0; off >>= 1) acc += __shfl_down(acc, off, 64);
  if ((tid & 63) == 0) s_wave[tid >> 6] = acc;
  __syncthreads();
  if (tid == 0) {
    out[0] = (s_wave[0] + s_wave[1] + s_wave[2] + s_wave[3]) * INV_BN + 0.5f;
  }
}

extern "C" void kernel_launch(void* const* d_in, const int* in_sizes, int n_in,
                              void* d_out, int out_size, void* d_ws, size_t ws_size,
                              hipStream_t stream) {
  const float* gout = (const float*)d_in[0];  // (B,3,7)
  const float* gtgt = (const float*)d_in[1];  // (B,3,5)
  float* ws = (float*)d_ws;                   // >= 4096 floats (16 KB)
  float* out = (float*)d_out;

  loc_loss_kernel<<<NBLK, 256, 0, stream>>>(gout, gtgt, ws);
  loc_loss_finalize<<<1, 256, 0, stream>>>(ws, out);
}